// Round 8
// baseline (341.865 us; speedup 1.0000x reference)
//
#include <hip/hip_runtime.h>

#define IN_DIM 4096
#define N_SOMA 16384
#define N_NEURONS 1024
#define BATCH 256
#define NEG_SLOPE 0.1f

typedef float f32x4 __attribute__((ext_vector_type(4)));

__device__ __forceinline__ int mbcnt64(unsigned long long m) {
    return __builtin_amdgcn_mbcnt_hi((unsigned)(m >> 32),
                                     __builtin_amdgcn_mbcnt_lo((unsigned)m, 0));
}

// ---------------------------------------------------------------------------
// Kernel 1: transpose x [BATCH][IN_DIM] -> xT [IN_DIM][BATCH]
// ---------------------------------------------------------------------------
__global__ __launch_bounds__(256) void transpose_x_kernel(
    const float* __restrict__ x, float* __restrict__ xT) {
    __shared__ float tile[64][65];
    const int i0 = blockIdx.x * 64;
    const int b0 = blockIdx.y * 64;
    const int lane = threadIdx.x & 63;
    const int grp  = threadIdx.x >> 6;

#pragma unroll
    for (int r = 0; r < 16; ++r) {
        const int b_local = grp * 16 + r;
        tile[b_local][lane] = x[(size_t)(b0 + b_local) * IN_DIM + i0 + lane];
    }
    __syncthreads();
#pragma unroll
    for (int r = 0; r < 16; ++r) {
        const int i_local = grp * 16 + r;
        xT[(size_t)(i0 + i_local) * BATCH + b0 + lane] = tile[lane][i_local];
    }
}

// ---------------------------------------------------------------------------
// Kernel 2: fused two-phase (R4 structure, proven correct/fast-ish) with the
// compute phase restructured for L2 residency:
//   STAGE:   wave w streams+compacts rows {w,4+w,8+w,12+w} into LDS
//            (mbcnt-based rank; stream-bound ~44us, VALU fits underneath).
//   COMPUTE: wave w owns rows {4w..4w+3}; batch swept in TWO sequential
//            128-column passes, so the chip-wide hot slice of xT is 2 MB
//            per XCD -> gathers hit L2 (was: 4 MB random -> L3-bound).
//            Pair base offsets hoisted to SGPR via readfirstlane; 8
//            independent FMA chains per wave for ILP.
//   Final: cross-wave partial-sum reduce in LDS, soma LeakyReLU, store.
// ---------------------------------------------------------------------------
__global__ __launch_bounds__(256, 4) void fused_kernel(
    const float* __restrict__ dW, const float* __restrict__ db,
    const float* __restrict__ sW, const float* __restrict__ sb,
    const float* __restrict__ xT, float* __restrict__ out) {
    const int bid = blockIdx.x;
    // XCD-chunked swizzle: 128 consecutive neurons per XCD.
    const int n = (bid & 7) * (N_NEURONS / 8) + (bid >> 3);
    const int t = threadIdx.x;
    const int wave = t >> 6;
    const int lane = t & 63;

    __shared__ int2  s_pair[16][32];   // (element offset idx*BATCH, w bits)
    __shared__ float s_sw[16];
    __shared__ float s_db[16];
    __shared__ float s_part[4][BATCH];

    // Defensive zero-init: an under-full row contributes 0 * xT[0] = 0.
    {
        int2* p = &s_pair[0][0];
        p[t] = make_int2(0, 0);
        p[t + 256] = make_int2(0, 0);
    }
    if (t < 16) {
        s_sw[t] = sW[(size_t)n * N_SOMA + n * 16 + t];
        s_db[t] = db[n * 16 + t];
    }
    __syncthreads();

    // ---- STAGE ----
    for (int rr = 0; rr < 4; ++rr) {
        const int r = rr * 4 + wave;
        const f32x4* row4 = reinterpret_cast<const f32x4*>(
            dW + (size_t)(n * 16 + r) * IN_DIM);
        f32x4 v[16];
#pragma unroll
        for (int k = 0; k < 16; ++k)
            v[k] = __builtin_nontemporal_load(row4 + k * 64 + lane);

        // Deterministic compaction, order = ascending global index
        // (k*256 + lane*4 + c). rank = base + below-lanes + my-prev-comps.
        int base = 0;
#pragma unroll
        for (int k = 0; k < 16; ++k) {
            float e[4] = {v[k].x, v[k].y, v[k].z, v[k].w};
            unsigned long long m[4];
#pragma unroll
            for (int c = 0; c < 4; ++c) m[c] = __ballot(e[c] != 0.f);
            const int below = mbcnt64(m[0]) + mbcnt64(m[1]) +
                              mbcnt64(m[2]) + mbcnt64(m[3]);
            int myprev = 0;
#pragma unroll
            for (int c = 0; c < 4; ++c) {
                if (e[c] != 0.f) {
                    const int pos = base + below + myprev;
                    if (pos < 32)
                        s_pair[r][pos] =
                            make_int2((((k * 64 + lane) << 2) + c) << 8,
                                      __float_as_int(e[c]));
                    ++myprev;
                }
            }
#pragma unroll
            for (int c = 0; c < 4; ++c) base += __popcll(m[c]);
        }
    }
    __syncthreads();

    // ---- COMPUTE: two sequential 128-column passes ----
    const int r0 = wave * 4;
    float psum[4] = {0.f, 0.f, 0.f, 0.f};

#pragma unroll
    for (int pass = 0; pass < 2; ++pass) {
        float dacc[4][2];
#pragma unroll
        for (int rr = 0; rr < 4; ++rr) {
            dacc[rr][0] = s_db[r0 + rr];
            dacc[rr][1] = s_db[r0 + rr];
        }
#pragma unroll
        for (int j = 0; j < 32; ++j) {
#pragma unroll
            for (int rr = 0; rr < 4; ++rr) {
                const int2 p = s_pair[r0 + rr][j];        // LDS broadcast
                const int ro = __builtin_amdgcn_readfirstlane(p.x);
                const float w = __int_as_float(p.y);
                const float* src = xT + ro + pass * 128 + lane;
                dacc[rr][0] = fmaf(w, src[0], dacc[rr][0]);
                dacc[rr][1] = fmaf(w, src[64], dacc[rr][1]);
            }
        }
#pragma unroll
        for (int rr = 0; rr < 4; ++rr) {
#pragma unroll
            for (int gg = 0; gg < 2; ++gg) {
                float d = dacc[rr][gg];
                d = (d >= 0.f) ? d : NEG_SLOPE * d;
                psum[pass * 2 + gg] = fmaf(s_sw[r0 + rr], d, psum[pass * 2 + gg]);
            }
        }
    }

#pragma unroll
    for (int g = 0; g < 4; ++g)
        s_part[wave][g * 64 + lane] = psum[g];
    __syncthreads();

    float sacc = sb[n] + s_part[0][t] + s_part[1][t] + s_part[2][t] + s_part[3][t];
    sacc = (sacc >= 0.f) ? sacc : NEG_SLOPE * sacc;
    out[(size_t)t * N_NEURONS + n] = sacc;
}

// ---------------------------------------------------------------------------
extern "C" void kernel_launch(void* const* d_in, const int* in_sizes, int n_in,
                              void* d_out, int out_size, void* d_ws, size_t ws_size,
                              hipStream_t stream) {
    const float* x  = (const float*)d_in[0];  // [256][4096]
    const float* dW = (const float*)d_in[1];  // [16384][4096] (pre-masked)
    const float* db = (const float*)d_in[2];  // [16384]
    const float* sW = (const float*)d_in[3];  // [1024][16384] (pre-masked)
    const float* sb = (const float*)d_in[4];  // [1024]
    float* out = (float*)d_out;               // [256][1024]

    float* xT = (float*)d_ws;                 // [4096][256]  4 MB

    transpose_x_kernel<<<dim3(IN_DIM / 64, BATCH / 64), 256, 0, stream>>>(x, xT);
    fused_kernel<<<N_NEURONS, 256, 0, stream>>>(dW, db, sW, sb, xT, out);
}

// Round 9
// 124.343 us; speedup vs baseline: 2.7494x; 2.7494x over previous
//
#include <hip/hip_runtime.h>

#define IN_DIM 4096
#define N_SOMA 16384
#define N_NEURONS 1024
#define BATCH 256
#define NEG_SLOPE 0.1f

typedef float f32x4 __attribute__((ext_vector_type(4)));

// ---------------------------------------------------------------------------
// Kernel 1: transpose x [BATCH][IN_DIM] -> xT [IN_DIM][BATCH]
// ---------------------------------------------------------------------------
__global__ __launch_bounds__(256) void transpose_x_kernel(
    const float* __restrict__ x, float* __restrict__ xT) {
    __shared__ float tile[64][65];
    const int i0 = blockIdx.x * 64;
    const int b0 = blockIdx.y * 64;
    const int lane = threadIdx.x & 63;
    const int grp  = threadIdx.x >> 6;

#pragma unroll
    for (int r = 0; r < 16; ++r) {
        const int b_local = grp * 16 + r;
        tile[b_local][lane] = x[(size_t)(b0 + b_local) * IN_DIM + i0 + lane];
    }
    __syncthreads();
#pragma unroll
    for (int r = 0; r < 16; ++r) {
        const int i_local = grp * 16 + r;
        xT[(size_t)(i0 + i_local) * BATCH + b0 + lane] = tile[lane][i_local];
    }
}

// ---------------------------------------------------------------------------
// Kernel 2: fused two-phase. STAGE is byte-for-byte Round 4 (proven: no
// spill, 84 us total). COMPUTE changed in exactly one way: gathers are
// dwordx4 (lane l covers columns 4l..4l+3), cutting per-CU VMEM issues
// 4x (32K -> 8K); wave w owns rows 4w..4w+3 with 4 independent float4
// FMA chains; final cross-wave LDS reduce.
// ---------------------------------------------------------------------------
__global__ __launch_bounds__(256, 4) void fused_kernel(
    const float* __restrict__ dW, const float* __restrict__ db,
    const float* __restrict__ sW, const float* __restrict__ sb,
    const float* __restrict__ xT, float* __restrict__ out) {
    const int bid = blockIdx.x;
    // XCD-chunked swizzle: 128 consecutive neurons per XCD.
    const int n = (bid & 7) * (N_NEURONS / 8) + (bid >> 3);
    const int t = threadIdx.x;
    const int wave = t >> 6;
    const int lane = t & 63;
    const unsigned long long lt = (1ull << lane) - 1ull;

    __shared__ int2  s_pair[16][32];   // (element offset idx*BATCH, w bits)
    __shared__ float s_sw[16];
    __shared__ float s_db[16];
    __shared__ f32x4 s_part[4][64];    // [wave][lane] partials, 4 cols each

    // Safety: an unfilled slot contributes w=0 * xT[0] = 0.
    {
        int2* p = &s_pair[0][0];
        p[t] = make_int2(0, 0);
        p[t + 256] = make_int2(0, 0);
    }
    if (t < 16) {
        s_sw[t] = sW[(size_t)n * N_SOMA + n * 16 + t];
        s_db[t] = db[n * 16 + t];
    }
    __syncthreads();

    // ---- STAGE (identical to Round 4) ----
    for (int rr = 0; rr < 4; ++rr) {
        const int r = rr * 4 + wave;
        const f32x4* row4 = reinterpret_cast<const f32x4*>(
            dW + (size_t)(n * 16 + r) * IN_DIM);
        f32x4 v[16];
#pragma unroll
        for (int k = 0; k < 16; ++k)
            v[k] = __builtin_nontemporal_load(row4 + k * 64 + lane);

        // Deterministic compaction, order = ascending global index
        // (k*256 + lane*4 + c).
        int base = 0;
#pragma unroll
        for (int k = 0; k < 16; ++k) {
            float e[4] = {v[k].x, v[k].y, v[k].z, v[k].w};
            unsigned long long m[4];
#pragma unroll
            for (int c = 0; c < 4; ++c) m[c] = __ballot(e[c] != 0.f);
            int below = 0;
#pragma unroll
            for (int c = 0; c < 4; ++c) below += __popcll(m[c] & lt);
            int myprev = 0;
#pragma unroll
            for (int c = 0; c < 4; ++c) {
                if (e[c] != 0.f) {
                    const int pos = base + below + myprev;
                    if (pos < 32)
                        s_pair[r][pos] =
                            make_int2((((k * 64 + lane) << 2) + c) << 8,
                                      __float_as_int(e[c]));
                    ++myprev;
                }
            }
#pragma unroll
            for (int c = 0; c < 4; ++c) base += __popcll(m[c]);
        }
    }
    __syncthreads();

    // ---- COMPUTE: wave w owns rows 4w..4w+3; lane covers cols 4l..4l+3 ----
    const int r0 = wave * 4;
    f32x4 psum = {0.f, 0.f, 0.f, 0.f};
#pragma unroll
    for (int rr = 0; rr < 4; ++rr) {
        const int r = r0 + rr;
        const float dbr = s_db[r];
        f32x4 dacc = {dbr, dbr, dbr, dbr};
#pragma unroll
        for (int j = 0; j < 32; ++j) {
            const int2 p = s_pair[r][j];     // broadcast LDS read
            const float w = __int_as_float(p.y);
            const f32x4 xv = *reinterpret_cast<const f32x4*>(xT + p.x + 4 * lane);
            dacc.x = fmaf(w, xv.x, dacc.x);
            dacc.y = fmaf(w, xv.y, dacc.y);
            dacc.z = fmaf(w, xv.z, dacc.z);
            dacc.w = fmaf(w, xv.w, dacc.w);
        }
        const float sw_ = s_sw[r];
        f32x4 d;
        d.x = (dacc.x >= 0.f) ? dacc.x : NEG_SLOPE * dacc.x;
        d.y = (dacc.y >= 0.f) ? dacc.y : NEG_SLOPE * dacc.y;
        d.z = (dacc.z >= 0.f) ? dacc.z : NEG_SLOPE * dacc.z;
        d.w = (dacc.w >= 0.f) ? dacc.w : NEG_SLOPE * dacc.w;
        psum.x = fmaf(sw_, d.x, psum.x);
        psum.y = fmaf(sw_, d.y, psum.y);
        psum.z = fmaf(sw_, d.z, psum.z);
        psum.w = fmaf(sw_, d.w, psum.w);
    }
    s_part[wave][lane] = psum;
    __syncthreads();

    // Column t partial of wave w sits at float offset w*256 + t.
    const float* pf = reinterpret_cast<const float*>(&s_part[0][0]);
    float sacc = sb[n] + pf[t] + pf[256 + t] + pf[512 + t] + pf[768 + t];
    sacc = (sacc >= 0.f) ? sacc : NEG_SLOPE * sacc;
    out[(size_t)t * N_NEURONS + n] = sacc;
}

// ---------------------------------------------------------------------------
extern "C" void kernel_launch(void* const* d_in, const int* in_sizes, int n_in,
                              void* d_out, int out_size, void* d_ws, size_t ws_size,
                              hipStream_t stream) {
    const float* x  = (const float*)d_in[0];  // [256][4096]
    const float* dW = (const float*)d_in[1];  // [16384][4096] (pre-masked)
    const float* db = (const float*)d_in[2];  // [16384]
    const float* sW = (const float*)d_in[3];  // [1024][16384] (pre-masked)
    const float* sb = (const float*)d_in[4];  // [1024]
    float* out = (float*)d_out;               // [256][1024]

    float* xT = (float*)d_ws;                 // [4096][256]  4 MB

    transpose_x_kernel<<<dim3(IN_DIM / 64, BATCH / 64), 256, 0, stream>>>(x, xT);
    fused_kernel<<<N_NEURONS, 256, 0, stream>>>(dW, db, sW, sb, xT, out);
}

// Round 10
// 84.394 us; speedup vs baseline: 4.0508x; 1.4734x over previous
//
#include <hip/hip_runtime.h>

#define IN_DIM 4096
#define N_SOMA 16384
#define N_NEURONS 1024
#define BATCH 256
#define NEG_SLOPE 0.1f

typedef float f32x4 __attribute__((ext_vector_type(4)));

// ---------------------------------------------------------------------------
// Kernel 1: transpose x [BATCH][IN_DIM] -> xT [IN_DIM][BATCH]  (R2-proven)
// ---------------------------------------------------------------------------
__global__ __launch_bounds__(256) void transpose_x_kernel(
    const float* __restrict__ x, float* __restrict__ xT) {
    __shared__ float tile[64][65];
    const int i0 = blockIdx.x * 64;
    const int b0 = blockIdx.y * 64;
    const int lane = threadIdx.x & 63;
    const int grp  = threadIdx.x >> 6;

#pragma unroll
    for (int r = 0; r < 16; ++r) {
        const int b_local = grp * 16 + r;
        tile[b_local][lane] = x[(size_t)(b0 + b_local) * IN_DIM + i0 + lane];
    }
    __syncthreads();
#pragma unroll
    for (int r = 0; r < 16; ++r) {
        const int i_local = grp * 16 + r;
        xT[(size_t)(i0 + i_local) * BATCH + b0 + lane] = tile[lane][i_local];
    }
}

// ---------------------------------------------------------------------------
// Kernel 2: pure-streaming sparse compaction (byte-for-byte R2 — proven).
// One wave per soma row; ballot/popcount deterministic compaction.
// ---------------------------------------------------------------------------
__global__ __launch_bounds__(256) void compact_kernel(
    const float* __restrict__ W, int* __restrict__ cIdx, float* __restrict__ cW) {
    const int wave = threadIdx.x >> 6;
    const int lane = threadIdx.x & 63;
    const int d = blockIdx.x * 4 + wave;

    const f32x4* row4 = reinterpret_cast<const f32x4*>(W + (size_t)d * IN_DIM);
    f32x4 v[16];
#pragma unroll
    for (int k = 0; k < 16; ++k) {
        v[k] = __builtin_nontemporal_load(row4 + k * 64 + lane);
    }

    const unsigned long long lt = (1ull << lane) - 1ull;
    int* __restrict__ rowIdx = cIdx + (size_t)d * 32;
    float* __restrict__ rowW = cW + (size_t)d * 32;

    int base = 0;
#pragma unroll
    for (int k = 0; k < 16; ++k) {
        float e[4] = {v[k].x, v[k].y, v[k].z, v[k].w};
        unsigned long long m[4];
#pragma unroll
        for (int c = 0; c < 4; ++c) m[c] = __ballot(e[c] != 0.f);

        int below = 0;
#pragma unroll
        for (int c = 0; c < 4; ++c) below += __popcll(m[c] & lt);

        int myprev = 0;
#pragma unroll
        for (int c = 0; c < 4; ++c) {
            if (e[c] != 0.f) {
                const int pos = base + below + myprev;
                if (pos < 32) {
                    rowIdx[pos] = ((k * 64 + lane) << 2) + c;
                    rowW[pos] = e[c];
                }
                ++myprev;
            }
        }
#pragma unroll
        for (int c = 0; c < 4; ++c) base += __popcll(m[c]);
    }
}

// ---------------------------------------------------------------------------
// Kernel 3: fused dendrite+soma for a 128-COLUMN HALF of the batch.
// Launched twice (colBase = 0, 128). Per pass the chip-wide hot slice of
// xT is [4096][128] = 2 MB -> L2-resident per XCD (was 4 MB = exactly L2
// capacity -> thrash -> L3-bound 38us). Block = 1 neuron x 128 cols x 2
// row-halves (waves 0,1 -> rows 0-7; waves 2,3 -> rows 8-15), scalar
// gathers identical codegen to R2's proven kernel, VGPR-lean.
// ---------------------------------------------------------------------------
__global__ __launch_bounds__(256) void neuron_kernel(
    const int* __restrict__ cIdx, const float* __restrict__ cW,
    const float* __restrict__ db, const float* __restrict__ sW,
    const float* __restrict__ sb, const float* __restrict__ xT,
    float* __restrict__ out, int colBase) {
    const int bid = blockIdx.x;
    // XCD-chunked swizzle: 128 consecutive neurons per XCD -> output-line
    // write merging within one L2.
    const int n = (bid & 7) * (N_NEURONS / 8) + (bid >> 3);
    const int t = threadIdx.x;
    const int col  = t & 127;   // 0..127 within this pass
    const int half = t >> 7;    // rows 8*half .. 8*half+7

    __shared__ int   s_idx[512];
    __shared__ float s_w[512];
    __shared__ float s_sw[16];
    __shared__ float s_db[16];
    __shared__ float s_part[2][128];

    {
        const int* gi = cIdx + (size_t)n * 512;
        const float* gw = cW + (size_t)n * 512;
        s_idx[t]       = gi[t] << 8;        // pre-scale: idx * BATCH
        s_idx[t + 256] = gi[t + 256] << 8;
        s_w[t]         = gw[t];
        s_w[t + 256]   = gw[t + 256];
    }
    if (t < 16) {
        s_sw[t] = sW[(size_t)n * N_SOMA + n * 16 + t];
        s_db[t] = db[n * 16 + t];
    }
    __syncthreads();

    const float* __restrict__ xcol = xT + colBase + col;
    float psum = 0.f;
#pragma unroll
    for (int rr = 0; rr < 8; ++rr) {
        const int r = half * 8 + rr;
        float dacc = s_db[r];
#pragma unroll
        for (int j = 0; j < 32; ++j) {
            dacc = fmaf(s_w[r * 32 + j], xcol[s_idx[r * 32 + j]], dacc);
        }
        dacc = (dacc >= 0.f) ? dacc : NEG_SLOPE * dacc;
        psum = fmaf(s_sw[r], dacc, psum);
    }
    s_part[half][col] = psum;
    __syncthreads();

    if (t < 128) {
        float sacc = sb[n] + s_part[0][t] + s_part[1][t];
        sacc = (sacc >= 0.f) ? sacc : NEG_SLOPE * sacc;
        out[(size_t)(colBase + t) * N_NEURONS + n] = sacc;
    }
}

// ---------------------------------------------------------------------------
extern "C" void kernel_launch(void* const* d_in, const int* in_sizes, int n_in,
                              void* d_out, int out_size, void* d_ws, size_t ws_size,
                              hipStream_t stream) {
    const float* x  = (const float*)d_in[0];  // [256][4096]
    const float* dW = (const float*)d_in[1];  // [16384][4096] (pre-masked)
    const float* db = (const float*)d_in[2];  // [16384]
    const float* sW = (const float*)d_in[3];  // [1024][16384] (pre-masked)
    const float* sb = (const float*)d_in[4];  // [1024]
    float* out = (float*)d_out;               // [256][1024]

    float* xT   = (float*)d_ws;                          // [4096][256]   4 MB
    int*   cIdx = (int*)(xT + (size_t)IN_DIM * BATCH);   // [16384][32]   2 MB
    float* cW   = (float*)(cIdx + (size_t)N_SOMA * 32);  // [16384][32]   2 MB

    transpose_x_kernel<<<dim3(IN_DIM / 64, BATCH / 64), 256, 0, stream>>>(x, xT);
    compact_kernel<<<N_SOMA / 4, 256, 0, stream>>>(dW, cIdx, cW);
    neuron_kernel<<<N_NEURONS, 256, 0, stream>>>(cIdx, cW, db, sW, sb, xT, out, 0);
    neuron_kernel<<<N_NEURONS, 256, 0, stream>>>(cIdx, cW, db, sW, sb, xT, out, 128);
}